// Round 1
// baseline (465.642 us; speedup 1.0000x reference)
//
#include <hip/hip_runtime.h>
#include <math.h>

#define P_N 4096
#define T_N 128
#define A_N 32
#define K_N 409          // int(4096 * 0.1)
#define TEMP_C 0.5f
#define MOM_C 0.1f
#define MIN_STD_C 0.05f
#define INF_F 1e30f

// ---------------------------------------------------------------------------
// Kernel 1: DTW min-plus DP. One wave = 2 particles (one per 32-lane half).
// Lane l (0..31 within half) owns DP columns 4l+1..4l+4 (1-indexed).
// Row recurrence new[j] = min(min(prev[j],prev[j-1]), new[j-1]) + c[j] is an
// affine (min,+) recurrence x -> min(x + C, B); compositions are scanned
// across lanes with shfl_up (width=32), 5 steps.
// ---------------------------------------------------------------------------
__global__ __launch_bounds__(256) void dtw_kernel(const float* __restrict__ obs,
                                                  float* __restrict__ dists) {
  const int tid  = threadIdx.x;
  const int wave = tid >> 6;
  const int lane = tid & 63;
  const int half = lane >> 5;
  const int l    = lane & 31;
  const int p    = blockIdx.x * 8 + wave * 2 + half;   // particle id

  const float4* row = (const float4*)(obs + (size_t)p * (T_N * T_N)) + l;

  // prev-row state: P1..P4 = D[i][4l+1..4l+4], p0 = D[i][4l]
  float P1 = INF_F, P2 = INF_F, P3 = INF_F, P4 = INF_F;
  float p0 = (l == 0) ? 0.0f : INF_F;   // D[0][0] = 0, rest of row 0 = INF

  // software prefetch, depth 2
  float4 cb0 = row[0];
  float4 cb1 = row[32];

  for (int r = 0; r < T_N; ++r) {
    float4 c = cb0;
    cb0 = cb1;
    int rn = r + 2; if (rn > T_N - 1) rn = T_N - 1;
    cb1 = row[rn * 32];

    // a[j] = min(prev[j], prev[j-1])
    float a1 = fminf(P1, p0);
    float a2 = fminf(P2, P1);
    float a3 = fminf(P3, P2);
    float a4 = fminf(P4, P3);

    // per-lane composite over 4 columns: f(x) = min(x + C, B)
    float B = a1 + c.x;
    float C = c.x;
    B = fminf(B + c.y, a2 + c.y); C += c.y;
    B = fminf(B + c.z, a3 + c.z); C += c.z;
    B = fminf(B + c.w, a4 + c.w); C += c.w;

    // inclusive scan across 32 lanes: compose (Cp,Bp) before (C,B)
    #pragma unroll
    for (int d = 1; d < 32; d <<= 1) {
      float Bp = __shfl_up(B, (unsigned)d, 32);
      float Cp = __shfl_up(C, (unsigned)d, 32);
      if (l >= d) { B = fminf(Bp + C, B); C = Cp + C; }
    }

    // carry-in for lane l = new[4l] = (excl composite)(INF) = B_incl(l-1)
    float x = __shfl_up(B, 1u, 32);
    if (l == 0) x = INF_F;   // boundary column: D[i][0] = INF for i>=1

    // apply: sequential within lane
    float n1 = fminf(a1, x)  + c.x;
    float n2 = fminf(a2, n1) + c.y;
    float n3 = fminf(a3, n2) + c.z;
    float n4 = fminf(a4, n3) + c.w;

    p0 = x; P1 = n1; P2 = n2; P3 = n3; P4 = n4;
  }

  if (l == 31) dists[p] = P4;   // D[T][T]
}

// ---------------------------------------------------------------------------
// Kernel 2: exact top-K selection (radix-select on fp32 bit patterns, which
// are monotone for non-negative dists), index-ordered tie-break to match
// lax.top_k, then softmax weights. Single block, 1024 threads.
// ---------------------------------------------------------------------------
__global__ __launch_bounds__(1024) void select_kernel(const float* __restrict__ dists,
                                                      int* __restrict__ elite_idx,
                                                      float* __restrict__ elite_wn,
                                                      float* __restrict__ meta) {
  __shared__ unsigned int skey[P_N];
  __shared__ unsigned int hist[256];
  __shared__ float elite_d[K_N];
  __shared__ int eqbuf[256];
  __shared__ float red[1024];
  __shared__ unsigned int sc_prefix, sc_minkey;
  __shared__ int sc_r, sc_cntlt, sc_cnteq;

  const int tid = threadIdx.x;

  // load keys to LDS + min-reduce
  unsigned int localmin = 0xFFFFFFFFu;
  for (int p = tid; p < P_N; p += 1024) {
    unsigned int k = __float_as_uint(dists[p]);
    skey[p] = k;
    if (k < localmin) localmin = k;
  }
  #pragma unroll
  for (int d = 32; d > 0; d >>= 1) {
    unsigned int o = __shfl_xor(localmin, (unsigned)d, 64);
    if (o < localmin) localmin = o;
  }
  if (tid == 0) { sc_minkey = 0xFFFFFFFFu; sc_cntlt = 0; sc_cnteq = 0;
                  sc_prefix = 0; sc_r = K_N - 1; }
  __syncthreads();
  if ((tid & 63) == 0) atomicMin(&sc_minkey, localmin);
  __syncthreads();

  // radix select: 4 passes, msb first
  unsigned int mask = 0;
  for (int shift = 24; shift >= 0; shift -= 8) {
    for (int b = tid; b < 256; b += 1024) hist[b] = 0;
    __syncthreads();
    unsigned int pref = sc_prefix;
    for (int p = tid; p < P_N; p += 1024) {
      unsigned int k = skey[p];
      if ((k & mask) == pref) atomicAdd(&hist[(k >> shift) & 255u], 1u);
    }
    __syncthreads();
    if (tid == 0) {
      int r = sc_r;
      unsigned int cum = 0;
      int bsel = 255;
      for (int b = 0; b < 256; ++b) {
        unsigned int h = hist[b];
        if ((unsigned int)r < cum + h) { bsel = b; break; }
        cum += h;
      }
      sc_prefix |= ((unsigned int)bsel) << shift;
      sc_r = r - (int)cum;
    }
    mask |= 0xFFu << shift;
    __syncthreads();
  }

  const unsigned int tk = sc_prefix;     // key of K-th smallest (rank K-1)
  const int needeq = sc_r + 1;           // how many ==tk entries to include

  // compaction: strict-less by atomic order (order-free), equals buffered
  for (int p = tid; p < P_N; p += 1024) {
    unsigned int k = skey[p];
    if (k < tk) {
      int pos = atomicAdd(&sc_cntlt, 1);
      elite_idx[pos] = p;
      elite_d[pos]   = __uint_as_float(k);
    } else if (k == tk) {
      int ep = atomicAdd(&sc_cnteq, 1);
      if (ep < 256) eqbuf[ep] = p;
    }
  }
  __syncthreads();
  if (tid == 0) {
    // take the `needeq` lowest indices among equals (lax.top_k tie-break)
    int cl = sc_cntlt;
    int ce = sc_cnteq; if (ce > 256) ce = 256;
    for (int rsel = 0; rsel < needeq; ++rsel) {
      int best = 0x7FFFFFFF, bi = 0;
      for (int m = 0; m < ce; ++m) {
        int v = eqbuf[m];
        if (v < best) { best = v; bi = m; }
      }
      eqbuf[bi] = 0x7FFFFFFF;
      elite_idx[cl + rsel] = best;
      elite_d[cl + rsel]   = __uint_as_float(tk);
    }
  }
  __syncthreads();

  // softmax weights: s_e = exp(TEMP*(min - d_e)); wn = s/S; ssum2 = sum(wn)
  const float minf = __uint_as_float(sc_minkey);
  float s = 0.0f;
  if (tid < K_N) s = expf(TEMP_C * (minf - elite_d[tid]));
  red[tid] = s;
  for (int d = 512; d > 0; d >>= 1) {
    __syncthreads();
    if (tid < d) red[tid] += red[tid + d];
  }
  __syncthreads();
  const float S = red[0];
  __syncthreads();
  const float wn = (tid < K_N) ? (s / S) : 0.0f;
  red[tid] = wn;
  for (int d = 512; d > 0; d >>= 1) {
    __syncthreads();
    if (tid < d) red[tid] += red[tid + d];
  }
  __syncthreads();
  if (tid < K_N) elite_wn[tid] = wn;
  if (tid == 0) meta[0] = red[0];   // ssum (≈1, but computed like reference)
}

// ---------------------------------------------------------------------------
// Kernel 3: per-t weighted mean/std over elite actions (gather only elites).
// Block = 256 threads = 8 elite-lanes x 32 action dims.
// ---------------------------------------------------------------------------
__global__ __launch_bounds__(256) void elite_stats_kernel(
    const float* __restrict__ noise, const float* __restrict__ means,
    const float* __restrict__ stds, const int* __restrict__ elite_idx,
    const float* __restrict__ elite_wn, const float* __restrict__ meta,
    float* __restrict__ out) {
  const int t = blockIdx.x;
  const int tid = threadIdx.x;
  const int a  = tid & 31;
  const int er = tid >> 5;   // 0..7
  __shared__ int   sidx[K_N];
  __shared__ float swn[K_N];
  __shared__ float sM[8][32];
  __shared__ float sQ[8][32];

  for (int e = tid; e < K_N; e += 256) { sidx[e] = elite_idx[e]; swn[e] = elite_wn[e]; }
  __syncthreads();

  const float mn = means[t * A_N + a];
  const float sd = stds[t * A_N + a];
  const float* nrow = noise + (size_t)t * P_N * A_N;

  float M = 0.0f, Q = 0.0f;
  for (int e = er; e < K_N; e += 8) {
    const int idx = sidx[e];
    const float w = swn[e];
    float x = mn + sd * nrow[idx * A_N + a];
    x = fminf(1.0f, fmaxf(-1.0f, x));   // clip(actions, -1, 1)
    M += w * x;
    Q += w * x * x;
  }
  sM[er][a] = M; sQ[er][a] = Q;
  __syncthreads();

  if (tid < 32) {
    float Ms = 0.0f, Qs = 0.0f;
    #pragma unroll
    for (int r = 0; r < 8; ++r) { Ms += sM[r][a]; Qs += sQ[r][a]; }
    const float ssum = meta[0];
    const float D = ssum + 1e-9f;
    const float mu = Ms / D;                                  // _mean
    float var = (Qs - 2.0f * mu * Ms + mu * mu * ssum) / D;   // sum w(x-mu)^2 / D
    float stdv = sqrtf(fmaxf(var, 0.0f));
    stdv = fminf(1.0f, fmaxf(MIN_STD_C, stdv));
    out[t * A_N + a]              = MOM_C * mn + (1.0f - MOM_C) * mu;  // means_new
    out[T_N * A_N + t * A_N + a]  = stdv;                              // _std
  }
}

// ---------------------------------------------------------------------------
extern "C" void kernel_launch(void* const* d_in, const int* in_sizes, int n_in,
                              void* d_out, int out_size, void* d_ws, size_t ws_size,
                              hipStream_t stream) {
  const float* obs   = (const float*)d_in[0];   // [P, T, T]
  const float* means = (const float*)d_in[1];   // [T, 1, A]
  const float* stds  = (const float*)d_in[2];   // [T, 1, A]
  const float* noise = (const float*)d_in[3];   // [T, P, A]
  float* out = (float*)d_out;                   // [2, T, 1, A]

  float* dists     = (float*)d_ws;              // P floats
  int*   elite_idx = (int*)(dists + P_N);       // K ints (padded to 512)
  float* elite_wn  = (float*)(elite_idx + 512); // K floats (padded to 512)
  float* meta      = elite_wn + 512;            // [0] = ssum

  dtw_kernel<<<P_N / 8, 256, 0, stream>>>(obs, dists);
  select_kernel<<<1, 1024, 0, stream>>>(dists, elite_idx, elite_wn, meta);
  elite_stats_kernel<<<T_N, 256, 0, stream>>>(noise, means, stds,
                                              elite_idx, elite_wn, meta, out);
}

// Round 2
// 448.327 us; speedup vs baseline: 1.0386x; 1.0386x over previous
//
#include <hip/hip_runtime.h>
#include <math.h>

#define P_N 4096
#define T_N 128
#define A_N 32
#define K_N 409          // int(4096 * 0.1)
#define TEMP_C 0.5f
#define MOM_C 0.1f
#define MIN_STD_C 0.05f
#define INF_F 1e30f

// DPP move: returns src shifted per ctrl; lanes with invalid source get `oldv`.
// ctrl: 0x110+N row_shr:N, 0x142 row_bcast:15, 0x138 wave_shr:1
#define DPPMOV(dst, src, ctrl, oldv)                                          \
  {                                                                           \
    union { float f; int i; } _a, _b, _r;                                     \
    _a.f = (src); _b.f = (oldv);                                              \
    _r.i = __builtin_amdgcn_update_dpp(_b.i, _a.i, (ctrl), 0xF, 0xF, false);  \
    (dst) = _r.f;                                                             \
  }

// ---------------------------------------------------------------------------
// Kernel 1: DTW min-plus DP. One wave = 2 particles (one per 32-lane half).
// Lane l (0..31 within half) owns DP columns 4l+1..4l+4 (1-indexed).
// Row recurrence new[j] = min(min(prev[j],prev[j-1]), new[j-1]) + c[j] is an
// affine (min,+) map x -> min(x + C, B); per-lane composites are combined
// with a 32-lane inclusive scan done entirely in DPP (VALU latency, no LDS).
// ---------------------------------------------------------------------------
__global__ __launch_bounds__(256) void dtw_kernel(const float* __restrict__ obs,
                                                  float* __restrict__ dists) {
  const int tid  = threadIdx.x;
  const int wave = tid >> 6;
  const int lane = tid & 63;
  const int half = lane >> 5;
  const int l    = lane & 31;
  const int p    = blockIdx.x * 8 + wave * 2 + half;   // particle id
  const bool is0 = (l == 0);

  const float4* row = (const float4*)(obs + (size_t)p * (T_N * T_N)) + l;

  // prev-row state: P1..P4 = D[i][4l+1..4l+4], p0 = D[i][4l]
  float P1 = INF_F, P2 = INF_F, P3 = INF_F, P4 = INF_F;
  float p0 = is0 ? 0.0f : INF_F;   // D[0][0] = 0, rest of row 0 = INF

  // software prefetch, depth 3
  float4 cb0 = row[0];
  float4 cb1 = row[32];
  float4 cb2 = row[64];

  for (int r = 0; r < T_N; ++r) {
    float4 c = cb0;
    cb0 = cb1; cb1 = cb2;
    int rn = r + 3; if (rn > T_N - 1) rn = T_N - 1;
    cb2 = row[rn * 32];

    // a[j] = min(prev[j], prev[j-1])
    float a1 = fminf(P1, p0);
    float a2 = fminf(P2, P1);
    float a3 = fminf(P3, P2);
    float a4 = fminf(P4, P3);

    // per-lane composite over 4 columns: f(x) = min(x + C, B)
    float B = a1 + c.x;
    B = fminf(B + c.y, a2 + c.y);
    B = fminf(B + c.z, a3 + c.z);
    B = fminf(B + c.w, a4 + c.w);
    float C = (c.x + c.y) + (c.z + c.w);

    // inclusive 32-lane scan via DPP: combine earlier segment (Bp,Cp) into
    // later (B,C):  B = min(Bp + C, B);  C = Cp + C.
    // Identity injection: Bp=INF, Cp=0 for lanes with no source.
    float Bp, Cp;
    DPPMOV(Bp, B, 0x111, INF_F); DPPMOV(Cp, C, 0x111, 0.0f);  // row_shr:1
    B = fminf(Bp + C, B); C = Cp + C;
    DPPMOV(Bp, B, 0x112, INF_F); DPPMOV(Cp, C, 0x112, 0.0f);  // row_shr:2
    B = fminf(Bp + C, B); C = Cp + C;
    DPPMOV(Bp, B, 0x114, INF_F); DPPMOV(Cp, C, 0x114, 0.0f);  // row_shr:4
    B = fminf(Bp + C, B); C = Cp + C;
    DPPMOV(Bp, B, 0x118, INF_F); DPPMOV(Cp, C, 0x118, 0.0f);  // row_shr:8
    B = fminf(Bp + C, B); C = Cp + C;
    DPPMOV(Bp, B, 0x142, INF_F); DPPMOV(Cp, C, 0x142, 0.0f);  // row_bcast:15
    B = fminf(Bp + C, B); C = Cp + C;

    // carry-in for lane l: new[4l] = B_incl(l-1); lane 0 of each half -> INF
    float x;
    DPPMOV(x, B, 0x138, INF_F);   // wave_shr:1
    x = is0 ? INF_F : x;          // fixes lane 0 AND lane 32 (cross-half leak)

    // apply: sequential within lane
    float n1 = fminf(a1, x)  + c.x;
    float n2 = fminf(a2, n1) + c.y;
    float n3 = fminf(a3, n2) + c.z;
    float n4 = fminf(a4, n3) + c.w;

    p0 = x; P1 = n1; P2 = n2; P3 = n3; P4 = n4;
  }

  if (l == 31) dists[p] = P4;   // D[T][T]
}

// ---------------------------------------------------------------------------
// Kernel 2: exact top-K selection (radix-select on fp32 bit patterns, which
// are monotone for non-negative dists), index-ordered tie-break to match
// lax.top_k, then softmax weights. Single block, 1024 threads.
// ---------------------------------------------------------------------------
__global__ __launch_bounds__(1024) void select_kernel(const float* __restrict__ dists,
                                                      int* __restrict__ elite_idx,
                                                      float* __restrict__ elite_wn,
                                                      float* __restrict__ meta) {
  __shared__ unsigned int skey[P_N];
  __shared__ __align__(16) unsigned int hist[256];
  __shared__ float elite_d[K_N];
  __shared__ int eqbuf[256];
  __shared__ float red[1024];
  __shared__ unsigned int sc_prefix, sc_minkey;
  __shared__ int sc_r, sc_cntlt, sc_cnteq;

  const int tid = threadIdx.x;

  // load keys to LDS + min-reduce
  unsigned int localmin = 0xFFFFFFFFu;
  for (int p = tid; p < P_N; p += 1024) {
    unsigned int k = __float_as_uint(dists[p]);
    skey[p] = k;
    if (k < localmin) localmin = k;
  }
  #pragma unroll
  for (int d = 32; d > 0; d >>= 1) {
    unsigned int o = __shfl_xor(localmin, (unsigned)d, 64);
    if (o < localmin) localmin = o;
  }
  if (tid == 0) { sc_minkey = 0xFFFFFFFFu; sc_cntlt = 0; sc_cnteq = 0;
                  sc_prefix = 0; sc_r = K_N - 1; }
  __syncthreads();
  if ((tid & 63) == 0) atomicMin(&sc_minkey, localmin);
  __syncthreads();

  // radix select: 4 passes, msb first
  unsigned int mask = 0;
  for (int shift = 24; shift >= 0; shift -= 8) {
    for (int b = tid; b < 256; b += 1024) hist[b] = 0;
    __syncthreads();
    unsigned int pref = sc_prefix;
    for (int p = tid; p < P_N; p += 1024) {
      unsigned int k = skey[p];
      if ((k & mask) == pref) atomicAdd(&hist[(k >> shift) & 255u], 1u);
    }
    __syncthreads();
    // wave 0: parallel 256-bucket prefix scan (4 buckets/lane) + rank search
    if (tid < 64) {
      unsigned h0 = hist[tid * 4 + 0], h1 = hist[tid * 4 + 1];
      unsigned h2 = hist[tid * 4 + 2], h3 = hist[tid * 4 + 3];
      unsigned s1 = h0 + h1, s2 = s1 + h2, s3 = s2 + h3;
      unsigned tot = s3;
      #pragma unroll
      for (int d = 1; d < 64; d <<= 1) {
        unsigned o = __shfl_up(tot, (unsigned)d, 64);
        if (tid >= d) tot += o;
      }
      unsigned base = tot - s3;            // exclusive start of bucket tid*4
      unsigned rr = (unsigned)sc_r;        // all lanes read BEFORE any write
      if (rr >= base && rr < base + s3) {  // exactly one lane true
        int bsel; unsigned lo;
        if (rr < base + h0)      { bsel = 0; lo = base; }
        else if (rr < base + s1) { bsel = 1; lo = base + h0; }
        else if (rr < base + s2) { bsel = 2; lo = base + s1; }
        else                     { bsel = 3; lo = base + s2; }
        sc_prefix |= (unsigned)(tid * 4 + bsel) << shift;
        sc_r = (int)(rr - lo);
      }
    }
    mask |= 0xFFu << shift;
    __syncthreads();
  }

  const unsigned int tk = sc_prefix;     // key of K-th smallest (rank K-1)
  const int needeq = sc_r + 1;           // how many ==tk entries to include

  // compaction: strict-less by atomic order (order-free), equals buffered
  for (int p = tid; p < P_N; p += 1024) {
    unsigned int k = skey[p];
    if (k < tk) {
      int pos = atomicAdd(&sc_cntlt, 1);
      elite_idx[pos] = p;
      elite_d[pos]   = __uint_as_float(k);
    } else if (k == tk) {
      int ep = atomicAdd(&sc_cnteq, 1);
      if (ep < 256) eqbuf[ep] = p;
    }
  }
  __syncthreads();
  if (tid == 0) {
    // take the `needeq` lowest indices among equals (lax.top_k tie-break)
    int cl = sc_cntlt;
    int ce = sc_cnteq; if (ce > 256) ce = 256;
    for (int rsel = 0; rsel < needeq; ++rsel) {
      int best = 0x7FFFFFFF, bi = 0;
      for (int m = 0; m < ce; ++m) {
        int v = eqbuf[m];
        if (v < best) { best = v; bi = m; }
      }
      eqbuf[bi] = 0x7FFFFFFF;
      elite_idx[cl + rsel] = best;
      elite_d[cl + rsel]   = __uint_as_float(tk);
    }
  }
  __syncthreads();

  // softmax weights: s_e = exp(TEMP*(min - d_e)); wn = s/S; ssum = sum(wn)
  const float minf = __uint_as_float(sc_minkey);
  float s = 0.0f;
  if (tid < K_N) s = expf(TEMP_C * (minf - elite_d[tid]));
  red[tid] = s;
  for (int d = 512; d > 0; d >>= 1) {
    __syncthreads();
    if (tid < d) red[tid] += red[tid + d];
  }
  __syncthreads();
  const float S = red[0];
  __syncthreads();
  const float wn = (tid < K_N) ? (s / S) : 0.0f;
  red[tid] = wn;
  for (int d = 512; d > 0; d >>= 1) {
    __syncthreads();
    if (tid < d) red[tid] += red[tid + d];
  }
  __syncthreads();
  if (tid < K_N) elite_wn[tid] = wn;
  if (tid == 0) meta[0] = red[0];   // ssum (≈1, but computed like reference)
}

// ---------------------------------------------------------------------------
// Kernel 3: per-t weighted mean/std over elite actions (gather only elites).
// Block = 256 threads = 8 elite-lanes x 32 action dims.
// ---------------------------------------------------------------------------
__global__ __launch_bounds__(256) void elite_stats_kernel(
    const float* __restrict__ noise, const float* __restrict__ means,
    const float* __restrict__ stds, const int* __restrict__ elite_idx,
    const float* __restrict__ elite_wn, const float* __restrict__ meta,
    float* __restrict__ out) {
  const int t = blockIdx.x;
  const int tid = threadIdx.x;
  const int a  = tid & 31;
  const int er = tid >> 5;   // 0..7
  __shared__ int   sidx[K_N];
  __shared__ float swn[K_N];
  __shared__ float sM[8][32];
  __shared__ float sQ[8][32];

  for (int e = tid; e < K_N; e += 256) { sidx[e] = elite_idx[e]; swn[e] = elite_wn[e]; }
  __syncthreads();

  const float mn = means[t * A_N + a];
  const float sd = stds[t * A_N + a];
  const float* nrow = noise + (size_t)t * P_N * A_N;

  float M = 0.0f, Q = 0.0f;
  for (int e = er; e < K_N; e += 8) {
    const int idx = sidx[e];
    const float w = swn[e];
    float x = mn + sd * nrow[idx * A_N + a];
    x = fminf(1.0f, fmaxf(-1.0f, x));   // clip(actions, -1, 1)
    M += w * x;
    Q += w * x * x;
  }
  sM[er][a] = M; sQ[er][a] = Q;
  __syncthreads();

  if (tid < 32) {
    float Ms = 0.0f, Qs = 0.0f;
    #pragma unroll
    for (int r = 0; r < 8; ++r) { Ms += sM[r][a]; Qs += sQ[r][a]; }
    const float ssum = meta[0];
    const float D = ssum + 1e-9f;
    const float mu = Ms / D;                                  // _mean
    float var = (Qs - 2.0f * mu * Ms + mu * mu * ssum) / D;   // sum w(x-mu)^2 / D
    float stdv = sqrtf(fmaxf(var, 0.0f));
    stdv = fminf(1.0f, fmaxf(MIN_STD_C, stdv));
    out[t * A_N + a]              = MOM_C * mn + (1.0f - MOM_C) * mu;  // means_new
    out[T_N * A_N + t * A_N + a]  = stdv;                              // _std
  }
}

// ---------------------------------------------------------------------------
extern "C" void kernel_launch(void* const* d_in, const int* in_sizes, int n_in,
                              void* d_out, int out_size, void* d_ws, size_t ws_size,
                              hipStream_t stream) {
  const float* obs   = (const float*)d_in[0];   // [P, T, T]
  const float* means = (const float*)d_in[1];   // [T, 1, A]
  const float* stds  = (const float*)d_in[2];   // [T, 1, A]
  const float* noise = (const float*)d_in[3];   // [T, P, A]
  float* out = (float*)d_out;                   // [2, T, 1, A]

  float* dists     = (float*)d_ws;              // P floats
  int*   elite_idx = (int*)(dists + P_N);       // K ints (padded to 512)
  float* elite_wn  = (float*)(elite_idx + 512); // K floats (padded to 512)
  float* meta      = elite_wn + 512;            // [0] = ssum

  dtw_kernel<<<P_N / 8, 256, 0, stream>>>(obs, dists);
  select_kernel<<<1, 1024, 0, stream>>>(dists, elite_idx, elite_wn, meta);
  elite_stats_kernel<<<T_N, 256, 0, stream>>>(noise, means, stds,
                                              elite_idx, elite_wn, meta, out);
}

// Round 4
// 429.615 us; speedup vs baseline: 1.0839x; 1.0436x over previous
//
#include <hip/hip_runtime.h>
#include <math.h>

#define P_N 4096
#define T_N 128
#define A_N 32
#define K_N 409          // int(4096 * 0.1)
#define TEMP_C 0.5f
#define MOM_C 0.1f
#define MIN_STD_C 0.05f
#define INF_F 1e30f

// native vector type (Clang ext_vector) — required by __builtin_nontemporal_load
typedef float vfloat4 __attribute__((ext_vector_type(4)));

// DPP move: returns src shifted per ctrl; lanes with invalid source get `oldv`.
// ctrl: 0x110+N row_shr:N, 0x142 row_bcast:15, 0x138 wave_shr:1
#define DPPMOV(dst, src, ctrl, oldv)                                          \
  {                                                                           \
    union { float f; int i; } _a, _b, _r;                                     \
    _a.f = (src); _b.f = (oldv);                                              \
    _r.i = __builtin_amdgcn_update_dpp(_b.i, _a.i, (ctrl), 0xF, 0xF, false);  \
    (dst) = _r.f;                                                             \
  }

// ---------------------------------------------------------------------------
// Kernel 1: DTW min-plus DP. One wave = 2 particles (one per 32-lane half).
// Lane l (0..31 within half) owns DP columns 4l+1..4l+4 (1-indexed).
// Row recurrence new[j] = min(min(prev[j],prev[j-1]), new[j-1]) + c[j] is an
// affine (min,+) map x -> min(x + C, B); per-lane composites are combined
// with a 32-lane inclusive scan done entirely in DPP (VALU latency, no LDS).
// Loads are nontemporal (read-once stream) with depth-4 software prefetch.
// ---------------------------------------------------------------------------
__global__ __launch_bounds__(256) void dtw_kernel(const float* __restrict__ obs,
                                                  float* __restrict__ dists) {
  const int tid  = threadIdx.x;
  const int wave = tid >> 6;
  const int lane = tid & 63;
  const int half = lane >> 5;
  const int l    = lane & 31;
  const int p    = blockIdx.x * 8 + wave * 2 + half;   // particle id
  const bool is0 = (l == 0);

  const vfloat4* row = (const vfloat4*)(obs + (size_t)p * (T_N * T_N)) + l;

  // prev-row state: P1..P4 = D[i][4l+1..4l+4], p0 = D[i][4l]
  float P1 = INF_F, P2 = INF_F, P3 = INF_F, P4 = INF_F;
  float p0 = is0 ? 0.0f : INF_F;   // D[0][0] = 0, rest of row 0 = INF

  // software prefetch, depth 4, nontemporal (read-once)
  vfloat4 cb0 = __builtin_nontemporal_load(row);
  vfloat4 cb1 = __builtin_nontemporal_load(row + 32);
  vfloat4 cb2 = __builtin_nontemporal_load(row + 64);
  vfloat4 cb3 = __builtin_nontemporal_load(row + 96);

  for (int r = 0; r < T_N; ++r) {
    vfloat4 c = cb0;
    cb0 = cb1; cb1 = cb2; cb2 = cb3;
    int rn = r + 4; if (rn > T_N - 1) rn = T_N - 1;
    cb3 = __builtin_nontemporal_load(row + rn * 32);

    // a[j] = min(prev[j], prev[j-1])
    float a1 = fminf(P1, p0);
    float a2 = fminf(P2, P1);
    float a3 = fminf(P3, P2);
    float a4 = fminf(P4, P3);

    // per-lane composite over 4 columns: f(x) = min(x + C, B)
    float B = a1 + c.x;
    B = fminf(B + c.y, a2 + c.y);
    B = fminf(B + c.z, a3 + c.z);
    B = fminf(B + c.w, a4 + c.w);
    float C = (c.x + c.y) + (c.z + c.w);

    // inclusive 32-lane scan via DPP: combine earlier segment (Bp,Cp) into
    // later (B,C):  B = min(Bp + C, B);  C = Cp + C.
    // Identity injection: Bp=INF, Cp=0 for lanes with no source.
    float Bp, Cp;
    DPPMOV(Bp, B, 0x111, INF_F); DPPMOV(Cp, C, 0x111, 0.0f);  // row_shr:1
    B = fminf(Bp + C, B); C = Cp + C;
    DPPMOV(Bp, B, 0x112, INF_F); DPPMOV(Cp, C, 0x112, 0.0f);  // row_shr:2
    B = fminf(Bp + C, B); C = Cp + C;
    DPPMOV(Bp, B, 0x114, INF_F); DPPMOV(Cp, C, 0x114, 0.0f);  // row_shr:4
    B = fminf(Bp + C, B); C = Cp + C;
    DPPMOV(Bp, B, 0x118, INF_F); DPPMOV(Cp, C, 0x118, 0.0f);  // row_shr:8
    B = fminf(Bp + C, B); C = Cp + C;
    DPPMOV(Bp, B, 0x142, INF_F); DPPMOV(Cp, C, 0x142, 0.0f);  // row_bcast:15
    B = fminf(Bp + C, B); C = Cp + C;

    // carry-in for lane l: new[4l] = B_incl(l-1); lane 0 of each half -> INF
    float x;
    DPPMOV(x, B, 0x138, INF_F);   // wave_shr:1
    x = is0 ? INF_F : x;          // fixes lane 0 AND lane 32 (cross-half leak)

    // apply: sequential within lane
    float n1 = fminf(a1, x)  + c.x;
    float n2 = fminf(a2, n1) + c.y;
    float n3 = fminf(a3, n2) + c.z;
    float n4 = fminf(a4, n3) + c.w;

    p0 = x; P1 = n1; P2 = n2; P3 = n3; P4 = n4;
  }

  if (l == 31) dists[p] = P4;   // D[T][T]
}

// ---------------------------------------------------------------------------
// Kernel 2: exact top-K selection (radix-select on fp32 bit patterns, which
// are monotone for non-negative dists), index-ordered tie-break to match
// lax.top_k, then softmax weights. Single block, 1024 threads.
// Per-wave private histograms kill same-bucket LDS-atomic serialization
// (dists cluster into 2-3 exponent buckets in the MSB passes).
// ---------------------------------------------------------------------------
__global__ __launch_bounds__(1024) void select_kernel(const float* __restrict__ dists,
                                                      int* __restrict__ elite_idx,
                                                      float* __restrict__ elite_wn,
                                                      float* __restrict__ meta) {
  __shared__ unsigned int skey[P_N];            // 16 KB
  __shared__ unsigned int histw[16 * 256];      // 16 KB: per-wave histograms
  __shared__ float elite_d[K_N];
  __shared__ int eqbuf[256];
  __shared__ float wsum[16];
  __shared__ unsigned int sc_prefix, sc_minkey;
  __shared__ int sc_r, sc_cntlt, sc_cnteq;
  __shared__ float sS, sS2;

  const int tid  = threadIdx.x;
  const int wid  = tid >> 6;
  const int lane = tid & 63;

  // load keys to LDS + min-reduce
  unsigned int localmin = 0xFFFFFFFFu;
  for (int p = tid; p < P_N; p += 1024) {
    unsigned int k = __float_as_uint(dists[p]);
    skey[p] = k;
    if (k < localmin) localmin = k;
  }
  #pragma unroll
  for (int d = 32; d > 0; d >>= 1) {
    unsigned int o = __shfl_xor(localmin, (unsigned)d, 64);
    if (o < localmin) localmin = o;
  }
  if (tid == 0) { sc_minkey = 0xFFFFFFFFu; sc_cntlt = 0; sc_cnteq = 0;
                  sc_prefix = 0; sc_r = K_N - 1; }
  __syncthreads();
  if (lane == 0) atomicMin(&sc_minkey, localmin);
  __syncthreads();

  // radix select: 4 passes, msb first
  unsigned int mask = 0;
  for (int shift = 24; shift >= 0; shift -= 8) {
    for (int b = tid; b < 16 * 256; b += 1024) histw[b] = 0;
    __syncthreads();
    unsigned int pref = sc_prefix;
    for (int p = tid; p < P_N; p += 1024) {
      unsigned int k = skey[p];
      if ((k & mask) == pref)
        atomicAdd(&histw[wid * 256 + ((k >> shift) & 255u)], 1u);
    }
    __syncthreads();
    // fold 16 slices: thread b (<256) sums its bucket into slice 0
    if (tid < 256) {
      unsigned tot = 0;
      #pragma unroll
      for (int w = 0; w < 16; ++w) tot += histw[w * 256 + tid];
      histw[tid] = tot;
    }
    __syncthreads();
    // wave 0: parallel 256-bucket prefix scan (4 buckets/lane) + rank search
    if (tid < 64) {
      unsigned h0 = histw[tid * 4 + 0], h1 = histw[tid * 4 + 1];
      unsigned h2 = histw[tid * 4 + 2], h3 = histw[tid * 4 + 3];
      unsigned s1 = h0 + h1, s2 = s1 + h2, s3 = s2 + h3;
      unsigned tot = s3;
      #pragma unroll
      for (int d = 1; d < 64; d <<= 1) {
        unsigned o = __shfl_up(tot, (unsigned)d, 64);
        if (tid >= d) tot += o;
      }
      unsigned base = tot - s3;            // exclusive start of bucket tid*4
      unsigned rr = (unsigned)sc_r;        // all lanes read BEFORE any write
      if (rr >= base && rr < base + s3) {  // exactly one lane true
        int bsel; unsigned lo;
        if (rr < base + h0)      { bsel = 0; lo = base; }
        else if (rr < base + s1) { bsel = 1; lo = base + h0; }
        else if (rr < base + s2) { bsel = 2; lo = base + s1; }
        else                     { bsel = 3; lo = base + s2; }
        sc_prefix |= (unsigned)(tid * 4 + bsel) << shift;
        sc_r = (int)(rr - lo);
      }
    }
    mask |= 0xFFu << shift;
    __syncthreads();
  }

  const unsigned int tk = sc_prefix;     // key of K-th smallest (rank K-1)
  const int needeq = sc_r + 1;           // how many ==tk entries to include

  // compaction: strict-less, ballot-aggregated (order is irrelevant
  // downstream; only membership matters). Equals buffered for tie-break.
  for (int p = tid; p < P_N; p += 1024) {
    unsigned int k = skey[p];
    const bool lt = (k < tk);
    unsigned long long m = __ballot(lt);
    int base = 0;
    if (lane == 0) base = atomicAdd(&sc_cntlt, (int)__popcll(m));
    base = __shfl(base, 0, 64);
    if (lt) {
      int pos = base + (int)__popcll(m & ((1ull << lane) - 1ull));
      elite_idx[pos] = p;
      elite_d[pos]   = __uint_as_float(k);
    } else if (k == tk) {
      int ep = atomicAdd(&sc_cnteq, 1);
      if (ep < 256) eqbuf[ep] = p;
    }
  }
  __syncthreads();
  if (tid == 0) {
    // take the `needeq` lowest indices among equals (lax.top_k tie-break)
    int cl = sc_cntlt;
    int ce = sc_cnteq; if (ce > 256) ce = 256;
    for (int rsel = 0; rsel < needeq; ++rsel) {
      int best = 0x7FFFFFFF, bi = 0;
      for (int m = 0; m < ce; ++m) {
        int v = eqbuf[m];
        if (v < best) { best = v; bi = m; }
      }
      eqbuf[bi] = 0x7FFFFFFF;
      elite_idx[cl + rsel] = best;
      elite_d[cl + rsel]   = __uint_as_float(tk);
    }
  }
  __syncthreads();

  // softmax weights: s_e = exp(TEMP*(min - d_e)); wn = s/S; ssum = sum(wn)
  const float minf = __uint_as_float(sc_minkey);
  float s = (tid < K_N) ? expf(TEMP_C * (minf - elite_d[tid])) : 0.0f;
  // wave-level sum then 16-partial fold
  float t1 = s;
  #pragma unroll
  for (int d = 32; d > 0; d >>= 1) t1 += __shfl_xor(t1, (unsigned)d, 64);
  if (lane == 0) wsum[wid] = t1;
  __syncthreads();
  if (tid == 0) {
    float acc = 0.0f;
    #pragma unroll
    for (int w = 0; w < 16; ++w) acc += wsum[w];
    sS = acc;
  }
  __syncthreads();
  const float S = sS;
  const float wn = (tid < K_N) ? (s / S) : 0.0f;
  float t2 = wn;
  #pragma unroll
  for (int d = 32; d > 0; d >>= 1) t2 += __shfl_xor(t2, (unsigned)d, 64);
  if (lane == 0) wsum[wid] = t2;
  __syncthreads();
  if (tid == 0) {
    float acc = 0.0f;
    #pragma unroll
    for (int w = 0; w < 16; ++w) acc += wsum[w];
    sS2 = acc;
  }
  __syncthreads();
  if (tid < K_N) elite_wn[tid] = wn;
  if (tid == 0) meta[0] = sS2;   // ssum (≈1, computed like reference)
}

// ---------------------------------------------------------------------------
// Kernel 3: per-t weighted mean/std over elite actions (gather only elites).
// Block = 512 threads = 16 elite-lanes x 32 action dims.
// ---------------------------------------------------------------------------
__global__ __launch_bounds__(512) void elite_stats_kernel(
    const float* __restrict__ noise, const float* __restrict__ means,
    const float* __restrict__ stds, const int* __restrict__ elite_idx,
    const float* __restrict__ elite_wn, const float* __restrict__ meta,
    float* __restrict__ out) {
  const int t = blockIdx.x;
  const int tid = threadIdx.x;
  const int a  = tid & 31;
  const int er = tid >> 5;   // 0..15
  __shared__ int   sidx[K_N];
  __shared__ float swn[K_N];
  __shared__ float sM[16][32];
  __shared__ float sQ[16][32];

  for (int e = tid; e < K_N; e += 512) { sidx[e] = elite_idx[e]; swn[e] = elite_wn[e]; }
  __syncthreads();

  const float mn = means[t * A_N + a];
  const float sd = stds[t * A_N + a];
  const float* nrow = noise + (size_t)t * P_N * A_N;

  float M = 0.0f, Q = 0.0f;
  for (int e = er; e < K_N; e += 16) {
    const int idx = sidx[e];
    const float w = swn[e];
    float x = mn + sd * nrow[idx * A_N + a];
    x = fminf(1.0f, fmaxf(-1.0f, x));   // clip(actions, -1, 1)
    M += w * x;
    Q += w * x * x;
  }
  sM[er][a] = M; sQ[er][a] = Q;
  __syncthreads();

  if (tid < 32) {
    float Ms = 0.0f, Qs = 0.0f;
    #pragma unroll
    for (int r = 0; r < 16; ++r) { Ms += sM[r][a]; Qs += sQ[r][a]; }
    const float ssum = meta[0];
    const float D = ssum + 1e-9f;
    const float mu = Ms / D;                                  // _mean
    float var = (Qs - 2.0f * mu * Ms + mu * mu * ssum) / D;   // sum w(x-mu)^2 / D
    float stdv = sqrtf(fmaxf(var, 0.0f));
    stdv = fminf(1.0f, fmaxf(MIN_STD_C, stdv));
    out[t * A_N + a]              = MOM_C * mn + (1.0f - MOM_C) * mu;  // means_new
    out[T_N * A_N + t * A_N + a]  = stdv;                              // _std
  }
}

// ---------------------------------------------------------------------------
extern "C" void kernel_launch(void* const* d_in, const int* in_sizes, int n_in,
                              void* d_out, int out_size, void* d_ws, size_t ws_size,
                              hipStream_t stream) {
  const float* obs   = (const float*)d_in[0];   // [P, T, T]
  const float* means = (const float*)d_in[1];   // [T, 1, A]
  const float* stds  = (const float*)d_in[2];   // [T, 1, A]
  const float* noise = (const float*)d_in[3];   // [T, P, A]
  float* out = (float*)d_out;                   // [2, T, 1, A]

  float* dists     = (float*)d_ws;              // P floats
  int*   elite_idx = (int*)(dists + P_N);       // K ints (padded to 512)
  float* elite_wn  = (float*)(elite_idx + 512); // K floats (padded to 512)
  float* meta      = elite_wn + 512;            // [0] = ssum

  dtw_kernel<<<P_N / 8, 256, 0, stream>>>(obs, dists);
  select_kernel<<<1, 1024, 0, stream>>>(dists, elite_idx, elite_wn, meta);
  elite_stats_kernel<<<T_N, 512, 0, stream>>>(noise, means, stds,
                                              elite_idx, elite_wn, meta, out);
}